// Round 8
// baseline (451.072 us; speedup 1.0000x reference)
//
#include <hip/hip_runtime.h>
#include <hip/hip_bf16.h>

#define S_LEN 2048
#define DMODEL 1024
#define NHEAD 16
#define DK 64
#define BS 4

typedef __attribute__((ext_vector_type(8))) short short8;
typedef __attribute__((ext_vector_type(4))) float f32x4;
typedef __attribute__((ext_vector_type(4))) ushort ushort4v;
typedef __attribute__((ext_vector_type(2))) unsigned int uint2v;

// exp(x*0.125) == exp2(x * 0.125*log2(e))
#define EXPSCALE 0.18033688011112042f

__device__ __forceinline__ ushort f2b(float f) {
  __hip_bfloat16 h = __float2bfloat16(f);
  return __builtin_bit_cast(ushort, h);
}

__device__ __forceinline__ float b2f(unsigned int bits16) {
  return __builtin_bit_cast(float, bits16 << 16);
}

__device__ __forceinline__ void gl_lds16(const void* g, void* l) {
  __builtin_amdgcn_global_load_lds(
      (const __attribute__((address_space(1))) void*)g,
      (__attribute__((address_space(3))) void*)l, 16, 0, 0);
}

// ---------------- conversion kernels ----------------

// k and v -> bf16 in one kernel
__global__ __launch_bounds__(256) void cvt2_kernel(
    const float* __restrict__ a, const float* __restrict__ b,
    ushort* __restrict__ oa, ushort* __restrict__ ob, int n4) {
  int idx = blockIdx.x * 256 + threadIdx.x;
  int stride = gridDim.x * 256;
  for (int i = idx; i < 2 * n4; i += stride) {
    const bool first = (i < n4);
    const int j = first ? i : i - n4;
    f32x4 v = first ? ((const f32x4*)a)[j] : ((const f32x4*)b)[j];
    ushort4v o;
    o[0] = f2b(v[0]); o[1] = f2b(v[1]); o[2] = f2b(v[2]); o[3] = f2b(v[3]);
    if (first) ((ushort4v*)oa)[j] = o; else ((ushort4v*)ob)[j] = o;
  }
}

// all four W (1024x1024 f32, K x N) -> Wt (N x K, bf16), z selects which
__global__ __launch_bounds__(256) void transW4_kernel(
    const float* __restrict__ W0, const float* __restrict__ W1,
    const float* __restrict__ W2, const float* __restrict__ W3,
    ushort* __restrict__ T0, ushort* __restrict__ T1,
    ushort* __restrict__ T2, ushort* __restrict__ T3) {
  const float* W;
  ushort* T;
  switch (blockIdx.z) {
    case 0: W = W0; T = T0; break;
    case 1: W = W1; T = T1; break;
    case 2: W = W2; T = T2; break;
    default: W = W3; T = T3; break;
  }
  __shared__ float t[32][33];
  const int n0 = blockIdx.x * 32, k0 = blockIdx.y * 32;
  const int tx = threadIdx.x, ty = threadIdx.y;  // (32,8)
#pragma unroll
  for (int i = 0; i < 4; i++)
    t[ty + i * 8][tx] = W[(size_t)(k0 + ty + i * 8) * DMODEL + n0 + tx];
  __syncthreads();
#pragma unroll
  for (int i = 0; i < 4; i++)
    T[(size_t)(n0 + ty + i * 8) * DMODEL + k0 + tx] = f2b(t[tx][ty + i * 8]);
}

// Vh (8192 x 1024 bf16) -> Vt (1024 x 8192 bf16)
__global__ __launch_bounds__(256) void transV_kernel(
    const ushort* __restrict__ Vh, ushort* __restrict__ Vt) {
  __shared__ ushort t[32][34];
  const int c0 = blockIdx.x * 32;  // Vh col (d index)
  const int r0 = blockIdx.y * 32;  // Vh row (token)
  const int tx = threadIdx.x, ty = threadIdx.y;
#pragma unroll
  for (int i = 0; i < 4; i++)
    t[ty + i * 8][tx] = Vh[(size_t)(r0 + ty + i * 8) * DMODEL + c0 + tx];
  __syncthreads();
#pragma unroll
  for (int i = 0; i < 4; i++)
    Vt[(size_t)(c0 + ty + i * 8) * (BS * S_LEN) + r0 + tx] = t[tx][ty + i * 8];
}

// ---------------- GEMM: C = A(MxK) * Bt(NxK)^T + bias ----------------
// 128x128 tile, BK=32, 256 threads (4 waves 2x2), m97 structure.
// XCD-aware block swizzle (grid % 8 == 0).
// MODE 0: merged QKV projection, N=3072. A = (bn<16)? A0 : A1.
//         cols 0..1023 -> C0(+bz), 1024..2047 -> C1(+b1), 2048.. -> C2(+b2),
//         all bf16 1024-wide.
// MODE 1: single f32 output (nontemporal), bias bz.
template <int MODE>
__global__ __launch_bounds__(256) void gemm_bt(
    const ushort* __restrict__ A0, const ushort* __restrict__ A1,
    const ushort* __restrict__ Bt,
    const float* __restrict__ bz, const float* __restrict__ b1,
    const float* __restrict__ b2,
    void* __restrict__ C0, void* __restrict__ C1, void* __restrict__ C2,
    int M, int N, int K) {
  __shared__ ushort Als[128 * 32];
  __shared__ ushort Bls[128 * 32];
  const int tid = threadIdx.x;
  const int lane = tid & 63;
  const int w = tid >> 6;
  const int lo = lane & 15, hi = lane >> 4;
  const int nb = N >> 7;
  const int swz = (blockIdx.x & 7) * (gridDim.x >> 3) + (blockIdx.x >> 3);
  const int bm = swz / nb, bn = swz % nb;
  const int m0 = bm << 7, n0 = bn << 7;
  const int wr = (w >> 1) << 6, wc = (w & 1) << 6;

  const ushort* A = (MODE == 0 && bn >= 16) ? A1 : A0;

  f32x4 acc[4][4] = {};

  const int c1 = tid, c2 = tid + 256;
  const int r1 = c1 >> 2, k1 = (c1 & 3) << 3;
  const int r2 = c2 >> 2, k2 = (c2 & 3) << 3;
  const ushort* Ap1 = A + (size_t)(m0 + r1) * K + k1;
  const ushort* Ap2 = A + (size_t)(m0 + r2) * K + k2;
  const ushort* Bp1 = Bt + (size_t)(n0 + r1) * K + k1;
  const ushort* Bp2 = Bt + (size_t)(n0 + r2) * K + k2;
  char* Al = (char*)Als;
  char* Bl = (char*)Bls;

  for (int k0 = 0; k0 < K; k0 += 32) {
    gl_lds16(Ap1 + k0, Al + c1 * 16);
    gl_lds16(Ap2 + k0, Al + c2 * 16);
    gl_lds16(Bp1 + k0, Bl + c1 * 16);
    gl_lds16(Bp2 + k0, Bl + c2 * 16);
    __syncthreads();
    short8 af[4], bf[4];
#pragma unroll
    for (int i = 0; i < 4; i++)
      af[i] = *(const short8*)(Als + (wr + i * 16 + lo) * 32 + hi * 8);
#pragma unroll
    for (int j = 0; j < 4; j++)
      bf[j] = *(const short8*)(Bls + (wc + j * 16 + lo) * 32 + hi * 8);
#pragma unroll
    for (int i = 0; i < 4; i++)
#pragma unroll
      for (int j = 0; j < 4; j++)
        acc[i][j] = __builtin_amdgcn_mfma_f32_16x16x32_bf16(af[i], bf[j], acc[i][j], 0, 0, 0);
    __syncthreads();
  }

#pragma unroll
  for (int j = 0; j < 4; j++) {
    const int col = n0 + wc + j * 16 + lo;
    if (MODE == 0) {
      const int sel = col >> 10;
      const int colm = col & 1023;
      const float* bp = (sel == 0) ? bz : (sel == 1) ? b1 : b2;
      ushort* dst = (sel == 0) ? (ushort*)C0 : (sel == 1) ? (ushort*)C1
                                                          : (ushort*)C2;
      const float bj = bp[colm];
#pragma unroll
      for (int i = 0; i < 4; i++) {
        const int row0 = m0 + wr + i * 16 + hi * 4;
#pragma unroll
        for (int r = 0; r < 4; r++)
          dst[(size_t)(row0 + r) * 1024 + colm] = f2b(acc[i][j][r] + bj);
      }
    } else {
      const float bj = bz[col];
#pragma unroll
      for (int i = 0; i < 4; i++) {
        const int row0 = m0 + wr + i * 16 + hi * 4;
#pragma unroll
        for (int r = 0; r < 4; r++)
          __builtin_nontemporal_store(
              acc[i][j][r] + bj, &((float*)C0)[(size_t)(row0 + r) * N + col]);
      }
    }
  }
}

// ---------------- fused causal attention (swapped QK^T) ----------------
// Block: (b, h, 128-row q-tile), 8 waves, wave owns 16 q-rows (q = w*16+lo).
// S^T = mfma(K_frag, Q_frag): lane (lo,hi) reg r = S[q][k=j*16+hi*4+r]
// -> per-lane scalar softmax denom. P tile -> per-wave swizzled bf16 LDS,
// read back row-major for coalesced attn stores (4 rows x 256B/instr,
// bf16->f32 expand). K/V staged in LDS (double-buffered, global_load_lds,
// XOR-swizzled source). Zero-fill of the masked region interleaved in
// sweep 1 (write pipe busy while stats compute; stores retire under the
// tile compute before the next barrier). LDS 48KB + VGPR<=84 -> 3 blk/CU.
__global__ __launch_bounds__(512, 6) void attn_kernel(
    const ushort* __restrict__ Qh, const ushort* __restrict__ Kh,
    const ushort* __restrict__ Vt, float* __restrict__ attn,
    ushort* __restrict__ Ah) {
  const int blk = blockIdx.x;
  const int t = 15 - (blk & 15);  // heavy tiles dispatch first
  const int h = (blk >> 4) & 15;
  const int b = blk >> 8;
  const int tid = threadIdx.x;
  const int w = tid >> 6;
  const int lane = tid & 63;
  const int lo = lane & 15, hi = lane >> 4;
  const int q0 = t << 7;
  const int qrow = w * 16 + lo;   // q row within the 128-row tile
  const int qg = q0 + qrow;       // absolute q row
  const int tok0 = b * S_LEN + q0 + w * 16;
  const int ktmax = 2 * t + 1;    // last 64-token kv tile (inclusive)
  const int ntiles = ktmax + 1;

  __shared__ ushort Kls[2][64 * 64];  // 2 x 8KB swizzled K tile
  __shared__ ushort Vls[2][64 * 64];  // 2 x 8KB swizzled V tile
  __shared__ ushort Pls[8][16 * 64];  // per-wave 2KB bf16 P tile (swizzled)

  short8 aq[2];  // Q rows, used as the MFMA B-operand
  {
    const ushort* qp = Qh + (size_t)(tok0 + lo) * DMODEL + h * DK + hi * 8;
    aq[0] = *(const short8*)qp;
    aq[1] = *(const short8*)(qp + 32);
  }

  const ushort* kbh = Kh + (size_t)(b * S_LEN) * DMODEL + h * DK;
  const ushort* vbh = Vt + (size_t)(h * DK) * (BS * S_LEN) + b * S_LEN;

  // staging geometry (proven): 512 threads, row = tid>>3 (0..63),
  // cb_lds = (tid&7)*16; global col bytes = cb_lds ^ ((row&7)<<4)
  const int srow = tid >> 3;
  const int scolb = ((tid & 7) << 4) ^ ((srow & 7) << 4);
  const ushort* ksrc = kbh + (size_t)srow * DMODEL + (scolb >> 1);
  const ushort* vsrc = vbh + (size_t)srow * (BS * S_LEN) + (scolb >> 1);

#define STAGE_K(buf, kt)                                                     \
  gl_lds16(ksrc + (size_t)(kt) * 64 * DMODEL, (char*)&Kls[(buf)][0] + tid * 16)
#define STAGE_V(buf, kt)                                                     \
  gl_lds16(vsrc + (size_t)(kt) * 64, (char*)&Vls[(buf)][0] + tid * 16)

  // K-fragments (A-operand): row = j*16+lo (k token), d = hi*8 (+32)
#define QKT(sa, cur)                                                         \
  __builtin_amdgcn_s_setprio(1);                                             \
  _Pragma("unroll") for (int j = 0; j < 4; j++) {                            \
    const int row = j * 16 + lo;                                             \
    short8 b0 = *(const short8*)((const char*)&Kls[(cur)][0] + row * 128 +   \
                                 ((hi * 16) ^ ((row & 7) << 4)));            \
    sa[j] = __builtin_amdgcn_mfma_f32_16x16x32_bf16(b0, aq[0], sa[j], 0, 0, 0); \
  }                                                                          \
  _Pragma("unroll") for (int j = 0; j < 4; j++) {                            \
    const int row = j * 16 + lo;                                             \
    short8 b1 = *(const short8*)((const char*)&Kls[(cur)][0] + row * 128 +   \
                                 ((64 + hi * 16) ^ ((row & 7) << 4)));       \
    sa[j] = __builtin_amdgcn_mfma_f32_16x16x32_bf16(b1, aq[1], sa[j], 0, 0, 0); \
  }                                                                          \
  __builtin_amdgcn_s_setprio(0);

  float* abase =
      attn + (size_t)(b * NHEAD + h) * S_LEN * S_LEN + (size_t)q0 * S_LEN;

  // zero-fill geometry (masked upper region), interleaved into sweep 1
  const int zc0 = ntiles << 6;        // first masked col
  const int zcol = zc0 + tid * 4;     // this thread's col within a row
  const bool zon = (zcol < S_LEN);
  const f32x4 zv = {0.0f, 0.0f, 0.0f, 0.0f};

  // ---- sweep 1: per-lane partial row sums of exp (K only) + zero-fill ----
  float lsum = 0.0f;
  STAGE_K(0, 0);
  for (int kt = 0; kt <= ktmax; ++kt) {
    const int cur = kt & 1;
    __syncthreads();  // staged data visible; prev buf's readers done
    if (kt < ktmax) STAGE_K(cur ^ 1, kt + 1);
    // interleaved zero-fill chunk: rows [kt*128/ntiles, (kt+1)*128/ntiles)
    if (zon) {
      const int r0 = (kt * 128) / ntiles;
      const int r1 = ((kt + 1) * 128) / ntiles;
      for (int row = r0; row < r1; ++row)
        __builtin_nontemporal_store(
            zv, (f32x4*)(abase + (size_t)row * S_LEN + zcol));
    }
    f32x4 sa[4] = {};
    QKT(sa, cur)
#pragma unroll
    for (int j = 0; j < 4; j++) {
#pragma unroll
      for (int r = 0; r < 4; r++) {
        const int kg = kt * 64 + j * 16 + hi * 4 + r;
        const float e = exp2f(sa[j][r] * EXPSCALE);
        lsum += (kg > qg) ? 0.0f : e;
      }
    }
  }
  // reduce across the 4 hi-groups holding the same q row
  lsum += __shfl_xor(lsum, 16);
  lsum += __shfl_xor(lsum, 32);
  const float invl = 1.0f / lsum;

  // ---- sweep 2: attn write + PV (K and V staged) ----
  f32x4 oacc[4] = {};

  __syncthreads();  // all waves done reading Kls from sweep 1
  STAGE_K(0, 0);
  STAGE_V(0, 0);
  for (int kt = 0; kt <= ktmax; ++kt) {
    const int cur = kt & 1;
    __syncthreads();
    if (kt < ktmax) { STAGE_K(cur ^ 1, kt + 1); STAGE_V(cur ^ 1, kt + 1); }
    f32x4 sa[4] = {};
    QKT(sa, cur)
    // P -> per-wave swizzled bf16 LDS tile (row = q = lo)
#pragma unroll
    for (int j = 0; j < 4; j++) {
      float p[4];
#pragma unroll
      for (int r = 0; r < 4; r++) {
        const int kg = kt * 64 + j * 16 + hi * 4 + r;
        p[r] = (kg > qg) ? 0.0f : exp2f(sa[j][r] * EXPSCALE) * invl;
      }
      const uint u0 = (uint)f2b(p[0]) | ((uint)f2b(p[1]) << 16);
      const uint u1 = (uint)f2b(p[2]) | ((uint)f2b(p[3]) << 16);
      uint2v uu = {u0, u1};
      *(uint2v*)((char*)&Pls[w][0] + lo * 128 +
                 ((j * 32 + hi * 8) ^ ((lo & 7) << 4))) = uu;
    }
    // coalesced attn stores: rows rr=hi+4*t2, cols lo*4..+3 (bf16->f32)
#pragma unroll
    for (int t2 = 0; t2 < 4; t2++) {
      const int rr = hi + 4 * t2;
      uint2v pv = *(const uint2v*)((const char*)&Pls[w][0] + rr * 128 +
                                   ((lo * 8) ^ ((rr & 7) << 4)));
      f32x4 o;
      o[0] = b2f(pv[0] & 0xffffu);
      o[1] = __builtin_bit_cast(float, pv[0] & 0xffff0000u);
      o[2] = b2f(pv[1] & 0xffffu);
      o[3] = __builtin_bit_cast(float, pv[1] & 0xffff0000u);
      __builtin_nontemporal_store(
          o,
          (f32x4*)(abase + (size_t)(w * 16 + rr) * S_LEN + kt * 64 + lo * 4));
    }
    // P A-fragments: row = q = lo, k = ks*32 + hi*8 ..+7 (proven read)
    short8 ap[2];
#pragma unroll
    for (int ks = 0; ks < 2; ks++)
      ap[ks] = *(const short8*)((const char*)&Pls[w][0] + lo * 128 +
                                ((ks * 64 + hi * 16) ^ ((lo & 7) << 4)));
    __builtin_amdgcn_s_setprio(1);
#pragma unroll
    for (int dj = 0; dj < 4; dj++) {
      const int row = dj * 16 + lo;
      const char* vrow = (const char*)&Vls[cur][0] + row * 128;
      short8 b0 = *(const short8*)(vrow + ((hi * 16) ^ ((row & 7) << 4)));
      short8 b1 = *(const short8*)(vrow + ((64 + hi * 16) ^ ((row & 7) << 4)));
      oacc[dj] = __builtin_amdgcn_mfma_f32_16x16x32_bf16(ap[0], b0, oacc[dj], 0, 0, 0);
      oacc[dj] = __builtin_amdgcn_mfma_f32_16x16x32_bf16(ap[1], b1, oacc[dj], 0, 0, 0);
    }
    __builtin_amdgcn_s_setprio(0);
  }

#pragma unroll
  for (int dj = 0; dj < 4; dj++)
#pragma unroll
    for (int r = 0; r < 4; r++)
      Ah[(size_t)(tok0 + hi * 4 + r) * DMODEL + h * DK + dj * 16 + lo] =
          f2b(oacc[dj][r]);
#undef STAGE_K
#undef STAGE_V
#undef QKT
}

// ---------------- launch ----------------

extern "C" void kernel_launch(void* const* d_in, const int* in_sizes, int n_in,
                              void* d_out, int out_size, void* d_ws,
                              size_t ws_size, hipStream_t stream) {
  const float* kin = (const float*)d_in[1];  // queries also come from k (ref quirk)
  const float* vin = (const float*)d_in[2];
  const float* Wq = (const float*)d_in[4];
  const float* bq = (const float*)d_in[5];
  const float* Wk = (const float*)d_in[6];
  const float* bk = (const float*)d_in[7];
  const float* Wv = (const float*)d_in[8];
  const float* bv = (const float*)d_in[9];
  const float* Wo = (const float*)d_in[10];
  const float* bo = (const float*)d_in[11];

  float* out = (float*)d_out;
  float* attn = out + (size_t)BS * S_LEN * DMODEL;

  char* ws = (char*)d_ws;
  const size_t MB = (size_t)1 << 20;
  ushort* kb    = (ushort*)(ws + 0 * MB);   // 16 MB; reused as Ah later
  ushort* vb    = (ushort*)(ws + 16 * MB);  // 16 MB; reused as Vt later
  ushort* Qh    = (ushort*)(ws + 32 * MB);  // 16 MB
  ushort* Kh    = (ushort*)(ws + 48 * MB);  // 16 MB
  ushort* Vh    = (ushort*)(ws + 64 * MB);  // 16 MB
  ushort* WqkvT = (ushort*)(ws + 80 * MB);  // 6 MB (Wq^T | Wk^T | Wv^T rows)
  ushort* WoT   = (ushort*)(ws + 86 * MB);  // 2 MB; total 88 MB

  const int NTOK4 = (BS * S_LEN * DMODEL) / 4;
  cvt2_kernel<<<4096, 256, 0, stream>>>(kin, vin, kb, vb, NTOK4);

  dim3 tb(32, 8);
  transW4_kernel<<<dim3(32, 32, 4), tb, 0, stream>>>(
      Wq, Wk, Wv, Wo, WqkvT, WqkvT + (size_t)DMODEL * DMODEL,
      WqkvT + (size_t)2 * DMODEL * DMODEL, WoT);

  // merged Q+K+V projection: N=3072, A per-column-block, split epilogue
  gemm_bt<0><<<64 * 24, 256, 0, stream>>>(
      kb, vb, WqkvT, bq, bk, bv, Qh, Kh, Vh, 8192, 3072, 1024);

  ushort* Vtp = vb;  // vb no longer needed
  transV_kernel<<<dim3(32, 256), tb, 0, stream>>>(Vh, Vtp);

  ushort* Ahp = kb;  // kb no longer needed
  attn_kernel<<<BS * NHEAD * (S_LEN / 128), 512, 0, stream>>>(Qh, Kh, Vtp, attn, Ahp);

  gemm_bt<1><<<64 * 8, 256, 0, stream>>>(
      Ahp, nullptr, WoT, bo, nullptr, nullptr, out, nullptr, nullptr,
      8192, 1024, 1024);
}

// Round 9
// 414.835 us; speedup vs baseline: 1.0874x; 1.0874x over previous
//
#include <hip/hip_runtime.h>
#include <hip/hip_bf16.h>

#define S_LEN 2048
#define DMODEL 1024
#define NHEAD 16
#define DK 64
#define BS 4

typedef __attribute__((ext_vector_type(8))) short short8;
typedef __attribute__((ext_vector_type(4))) float f32x4;
typedef __attribute__((ext_vector_type(4))) ushort ushort4v;

__device__ __forceinline__ ushort f2b(float f) {
  __hip_bfloat16 h = __float2bfloat16(f);
  return __builtin_bit_cast(ushort, h);
}

__device__ __forceinline__ void gl_lds16(const void* g, void* l) {
  __builtin_amdgcn_global_load_lds(
      (const __attribute__((address_space(1))) void*)g,
      (__attribute__((address_space(3))) void*)l, 16, 0, 0);
}

// ---------------- conversion kernels ----------------

// k and v -> bf16 in one kernel
__global__ __launch_bounds__(256) void cvt2_kernel(
    const float* __restrict__ a, const float* __restrict__ b,
    ushort* __restrict__ oa, ushort* __restrict__ ob, int n4) {
  int idx = blockIdx.x * 256 + threadIdx.x;
  int stride = gridDim.x * 256;
  for (int i = idx; i < 2 * n4; i += stride) {
    const bool first = (i < n4);
    const int j = first ? i : i - n4;
    f32x4 v = first ? ((const f32x4*)a)[j] : ((const f32x4*)b)[j];
    ushort4v o;
    o[0] = f2b(v[0]); o[1] = f2b(v[1]); o[2] = f2b(v[2]); o[3] = f2b(v[3]);
    if (first) ((ushort4v*)oa)[j] = o; else ((ushort4v*)ob)[j] = o;
  }
}

// all four W (1024x1024 f32, K x N) -> Wt (N x K, bf16), z selects which
__global__ __launch_bounds__(256) void transW4_kernel(
    const float* __restrict__ W0, const float* __restrict__ W1,
    const float* __restrict__ W2, const float* __restrict__ W3,
    ushort* __restrict__ T0, ushort* __restrict__ T1,
    ushort* __restrict__ T2, ushort* __restrict__ T3) {
  const float* W;
  ushort* T;
  switch (blockIdx.z) {
    case 0: W = W0; T = T0; break;
    case 1: W = W1; T = T1; break;
    case 2: W = W2; T = T2; break;
    default: W = W3; T = T3; break;
  }
  __shared__ float t[32][33];
  const int n0 = blockIdx.x * 32, k0 = blockIdx.y * 32;
  const int tx = threadIdx.x, ty = threadIdx.y;  // (32,8)
#pragma unroll
  for (int i = 0; i < 4; i++)
    t[ty + i * 8][tx] = W[(size_t)(k0 + ty + i * 8) * DMODEL + n0 + tx];
  __syncthreads();
#pragma unroll
  for (int i = 0; i < 4; i++)
    T[(size_t)(n0 + ty + i * 8) * DMODEL + k0 + tx] = f2b(t[tx][ty + i * 8]);
}

// ---------------- GEMM: C = A(MxK) * Bt(NxK)^T + bias ----------------
// 128x128 tile, BK=32, 256 threads (4 waves 2x2), m97 structure.
// QKMODE: N=2048 merged Q/K projection -> split column halves to Qh/Kh.
// VT: write C^T (bf16) to Cout laid out [N][M] (Vt layout), 8B token packs,
//     normal stores (L2 write-combining; Vt is read right after by attn).
template <bool F32OUT, bool QKMODE, bool VT>
__global__ __launch_bounds__(256) void gemm_bt(
    const ushort* __restrict__ A, const ushort* __restrict__ Bt,
    const float* __restrict__ bias, const float* __restrict__ bias1,
    void* __restrict__ Cout, void* __restrict__ Cout1,
    int M, int N, int K) {
  __shared__ ushort Als[128 * 32];
  __shared__ ushort Bls[128 * 32];
  const int tid = threadIdx.x;
  const int lane = tid & 63;
  const int w = tid >> 6;
  const int lo = lane & 15, hi = lane >> 4;
  const int nb = N >> 7;
  const int bm = blockIdx.x / nb, bn = blockIdx.x % nb;
  const int m0 = bm << 7, n0 = bn << 7;
  const int wr = (w >> 1) << 6, wc = (w & 1) << 6;

  f32x4 acc[4][4] = {};

  const int c1 = tid, c2 = tid + 256;
  const int r1 = c1 >> 2, k1 = (c1 & 3) << 3;
  const int r2 = c2 >> 2, k2 = (c2 & 3) << 3;
  const ushort* Ap1 = A + (size_t)(m0 + r1) * K + k1;
  const ushort* Ap2 = A + (size_t)(m0 + r2) * K + k2;
  const ushort* Bp1 = Bt + (size_t)(n0 + r1) * K + k1;
  const ushort* Bp2 = Bt + (size_t)(n0 + r2) * K + k2;
  char* Al = (char*)Als;
  char* Bl = (char*)Bls;

  for (int k0 = 0; k0 < K; k0 += 32) {
    gl_lds16(Ap1 + k0, Al + c1 * 16);
    gl_lds16(Ap2 + k0, Al + c2 * 16);
    gl_lds16(Bp1 + k0, Bl + c1 * 16);
    gl_lds16(Bp2 + k0, Bl + c2 * 16);
    __syncthreads();
    short8 af[4], bf[4];
#pragma unroll
    for (int i = 0; i < 4; i++)
      af[i] = *(const short8*)(Als + (wr + i * 16 + lo) * 32 + hi * 8);
#pragma unroll
    for (int j = 0; j < 4; j++)
      bf[j] = *(const short8*)(Bls + (wc + j * 16 + lo) * 32 + hi * 8);
#pragma unroll
    for (int i = 0; i < 4; i++)
#pragma unroll
      for (int j = 0; j < 4; j++)
        acc[i][j] = __builtin_amdgcn_mfma_f32_16x16x32_bf16(af[i], bf[j], acc[i][j], 0, 0, 0);
    __syncthreads();
  }

#pragma unroll
  for (int j = 0; j < 4; j++) {
    const int col = n0 + wc + j * 16 + lo;
    const float* bp = (QKMODE && col >= 1024) ? bias1 : bias;
    const int colm = QKMODE ? (col & 1023) : col;
    const int cN = QKMODE ? 1024 : N;
    const float bj = bp ? bp[colm] : 0.0f;
    if (VT) {
      // transposed store: Vt[col][tok], 4-token (8B) packs
#pragma unroll
      for (int i = 0; i < 4; i++) {
        const int row0 = m0 + wr + i * 16 + hi * 4;
        ushort4v pk;
#pragma unroll
        for (int r = 0; r < 4; r++) pk[r] = f2b(acc[i][j][r] + bj);
        *(ushort4v*)(&((ushort*)Cout)[(size_t)col * M + row0]) = pk;
      }
    } else {
#pragma unroll
      for (int i = 0; i < 4; i++) {
        const int row0 = m0 + wr + i * 16 + hi * 4;
#pragma unroll
        for (int r = 0; r < 4; r++) {
          float vv = acc[i][j][r] + bj;
          if (F32OUT) {
            __builtin_nontemporal_store(
                vv, &((float*)Cout)[(size_t)(row0 + r) * N + col]);
          } else {
            void* dst = (QKMODE && col >= 1024) ? Cout1 : Cout;
            ((ushort*)dst)[(size_t)(row0 + r) * cN + colm] = f2b(vv);
          }
        }
      }
    }
  }
}

// ---------------- fused causal attention (swapped QK^T) ----------------
// Block: (b, h, 128-row q-tile), 8 waves, wave owns 16 q-rows (q = w*16+lo).
// S^T = mfma(K_frag, Q_frag): lane (lo,hi) reg r = S[q][k=j*16+hi*4+r]
// -> per-lane scalar softmax denom. P tile -> per-wave swizzled f32 LDS,
// read back row-major for COALESCED attn stores (4 rows x 256B/instr) and
// as bf16 PV A-fragments. K/V staged in LDS (double-buffered,
// global_load_lds, XOR-swizzled source). Zero-fill interleaved in sweep 1.
// SWZ: 2-way bank aliasing max on write/read sides (free per m136).
#define SWZ(row) ((((row) & 7) << 5) ^ (((row) & 8) << 1))
__global__ __launch_bounds__(512) void attn_kernel(
    const ushort* __restrict__ Qh, const ushort* __restrict__ Kh,
    const ushort* __restrict__ Vt, float* __restrict__ attn,
    ushort* __restrict__ Ah) {
  const int blk = blockIdx.x;
  const int t = 15 - (blk & 15);  // heavy tiles dispatch first
  const int h = (blk >> 4) & 15;
  const int b = blk >> 8;
  const int tid = threadIdx.x;
  const int w = tid >> 6;
  const int lane = tid & 63;
  const int lo = lane & 15, hi = lane >> 4;
  const int q0 = t << 7;
  const int qrow = w * 16 + lo;   // q row within the 128-row tile
  const int qg = q0 + qrow;       // absolute q row
  const int tok0 = b * S_LEN + q0 + w * 16;
  const int ktmax = 2 * t + 1;    // last 64-token kv tile (inclusive)
  const int ntiles = ktmax + 1;

  __shared__ ushort Kls[2][64 * 64];  // 2 x 8KB swizzled K tile
  __shared__ ushort Vls[2][64 * 64];  // 2 x 8KB swizzled V tile
  __shared__ float Pf[8][16 * 64];    // per-wave 4KB swizzled f32 P tile

  short8 aq[2];  // Q rows, used as the MFMA B-operand
  {
    const ushort* qp = Qh + (size_t)(tok0 + lo) * DMODEL + h * DK + hi * 8;
    aq[0] = *(const short8*)qp;
    aq[1] = *(const short8*)(qp + 32);
  }

  const ushort* kbh = Kh + (size_t)(b * S_LEN) * DMODEL + h * DK;
  const ushort* vbh = Vt + (size_t)(h * DK) * (BS * S_LEN) + b * S_LEN;

  // staging geometry (proven): 512 threads, row = tid>>3 (0..63),
  // cb_lds = (tid&7)*16; global col bytes = cb_lds ^ ((row&7)<<4)
  const int srow = tid >> 3;
  const int scolb = ((tid & 7) << 4) ^ ((srow & 7) << 4);
  const ushort* ksrc = kbh + (size_t)srow * DMODEL + (scolb >> 1);
  const ushort* vsrc = vbh + (size_t)srow * (BS * S_LEN) + (scolb >> 1);

#define STAGE_K(buf, kt)                                                     \
  gl_lds16(ksrc + (size_t)(kt) * 64 * DMODEL, (char*)&Kls[(buf)][0] + tid * 16)
#define STAGE_V(buf, kt)                                                     \
  gl_lds16(vsrc + (size_t)(kt) * 64, (char*)&Vls[(buf)][0] + tid * 16)

  // K-fragments (A-operand): row = j*16+lo (k token), d = hi*8 (+32)
#define QKT(sa, cur)                                                         \
  __builtin_amdgcn_s_setprio(1);                                             \
  _Pragma("unroll") for (int j = 0; j < 4; j++) {                            \
    const int row = j * 16 + lo;                                             \
    short8 b0 = *(const short8*)((const char*)&Kls[(cur)][0] + row * 128 +   \
                                 ((hi * 16) ^ ((row & 7) << 4)));            \
    sa[j] = __builtin_amdgcn_mfma_f32_16x16x32_bf16(b0, aq[0], sa[j], 0, 0, 0); \
  }                                                                          \
  _Pragma("unroll") for (int j = 0; j < 4; j++) {                            \
    const int row = j * 16 + lo;                                             \
    short8 b1 = *(const short8*)((const char*)&Kls[(cur)][0] + row * 128 +   \
                                 ((64 + hi * 16) ^ ((row & 7) << 4)));       \
    sa[j] = __builtin_amdgcn_mfma_f32_16x16x32_bf16(b1, aq[1], sa[j], 0, 0, 0); \
  }                                                                          \
  __builtin_amdgcn_s_setprio(0);

  float* abase =
      attn + (size_t)(b * NHEAD + h) * S_LEN * S_LEN + (size_t)q0 * S_LEN;

  // zero-fill geometry (masked upper region), interleaved into sweep 1
  const int zc0 = ntiles << 6;        // first masked col
  const int zcol = zc0 + tid * 4;     // this thread's col within a row
  const bool zon = (zcol < S_LEN);
  const f32x4 zv = {0.0f, 0.0f, 0.0f, 0.0f};

  // ---- sweep 1: per-lane partial row sums of exp (K only) + zero-fill ----
  float lsum = 0.0f;
  STAGE_K(0, 0);
  for (int kt = 0; kt <= ktmax; ++kt) {
    const int cur = kt & 1;
    __syncthreads();  // staged data visible; prev buf's readers done
    if (kt < ktmax) STAGE_K(cur ^ 1, kt + 1);
    // interleaved zero-fill chunk: rows [kt*128/ntiles, (kt+1)*128/ntiles)
    if (zon) {
      const int r0 = (kt * 128) / ntiles;
      const int r1 = ((kt + 1) * 128) / ntiles;
      for (int row = r0; row < r1; ++row)
        __builtin_nontemporal_store(
            zv, (f32x4*)(abase + (size_t)row * S_LEN + zcol));
    }
    f32x4 sa[4] = {};
    QKT(sa, cur)
#pragma unroll
    for (int j = 0; j < 4; j++) {
#pragma unroll
      for (int r = 0; r < 4; r++) {
        const int kg = kt * 64 + j * 16 + hi * 4 + r;
        const float e = __expf(sa[j][r] * 0.125f);
        lsum += (kg > qg) ? 0.0f : e;
      }
    }
  }
  // reduce across the 4 hi-groups holding the same q row
  lsum += __shfl_xor(lsum, 16);
  lsum += __shfl_xor(lsum, 32);
  const float invl = 1.0f / lsum;

  // ---- sweep 2: attn write + PV (K and V staged) ----
  f32x4 oacc[4] = {};

  __syncthreads();  // all waves done reading Kls from sweep 1
  STAGE_K(0, 0);
  STAGE_V(0, 0);
  for (int kt = 0; kt <= ktmax; ++kt) {
    const int cur = kt & 1;
    __syncthreads();
    if (kt < ktmax) { STAGE_K(cur ^ 1, kt + 1); STAGE_V(cur ^ 1, kt + 1); }
    f32x4 sa[4] = {};
    QKT(sa, cur)
    // P -> per-wave swizzled f32 LDS tile (16 rows x 64 cols)
#pragma unroll
    for (int j = 0; j < 4; j++) {
      float p[4];
#pragma unroll
      for (int r = 0; r < 4; r++) {
        const int kg = kt * 64 + j * 16 + hi * 4 + r;
        p[r] = (kg > qg) ? 0.0f : __expf(sa[j][r] * 0.125f) * invl;
      }
      f32x4 pv4 = {p[0], p[1], p[2], p[3]};
      *(f32x4*)((char*)&Pf[w][0] + lo * 256 +
                ((j * 64 + hi * 16) ^ SWZ(lo))) = pv4;
    }
    // coalesced attn stores: 4 rows x 256B contiguous per instruction
#pragma unroll
    for (int t2 = 0; t2 < 4; t2++) {
      const int rr = hi + 4 * t2;
      f32x4 pv = *(const f32x4*)((const char*)&Pf[w][0] + rr * 256 +
                                 ((lo * 16) ^ SWZ(rr)));
      __builtin_nontemporal_store(
          pv,
          (f32x4*)(abase + (size_t)(w * 16 + rr) * S_LEN + kt * 64 + lo * 4));
    }
    // PV A-fragments: row = q = lo, k = ks*32 + hi*8 ..+7, from f32 tile
    short8 ap[2];
#pragma unroll
    for (int ks = 0; ks < 2; ks++) {
      const int base = ks * 128 + hi * 32;
      f32x4 u0 = *(const f32x4*)((const char*)&Pf[w][0] + lo * 256 +
                                 ((base) ^ SWZ(lo)));
      f32x4 u1 = *(const f32x4*)((const char*)&Pf[w][0] + lo * 256 +
                                 ((base + 16) ^ SWZ(lo)));
      short8 a;
      a[0] = f2b(u0[0]); a[1] = f2b(u0[1]); a[2] = f2b(u0[2]); a[3] = f2b(u0[3]);
      a[4] = f2b(u1[0]); a[5] = f2b(u1[1]); a[6] = f2b(u1[2]); a[7] = f2b(u1[3]);
      ap[ks] = a;
    }
    __builtin_amdgcn_s_setprio(1);
#pragma unroll
    for (int dj = 0; dj < 4; dj++) {
      const int row = dj * 16 + lo;
      const char* vrow = (const char*)&Vls[cur][0] + row * 128;
      short8 b0 = *(const short8*)(vrow + ((hi * 16) ^ ((row & 7) << 4)));
      short8 b1 = *(const short8*)(vrow + ((64 + hi * 16) ^ ((row & 7) << 4)));
      oacc[dj] = __builtin_amdgcn_mfma_f32_16x16x32_bf16(ap[0], b0, oacc[dj], 0, 0, 0);
      oacc[dj] = __builtin_amdgcn_mfma_f32_16x16x32_bf16(ap[1], b1, oacc[dj], 0, 0, 0);
    }
    __builtin_amdgcn_s_setprio(0);
  }

#pragma unroll
  for (int dj = 0; dj < 4; dj++)
#pragma unroll
    for (int r = 0; r < 4; r++)
      Ah[(size_t)(tok0 + hi * 4 + r) * DMODEL + h * DK + dj * 16 + lo] =
          f2b(oacc[dj][r]);
#undef STAGE_K
#undef STAGE_V
#undef QKT
}

// ---------------- launch ----------------

extern "C" void kernel_launch(void* const* d_in, const int* in_sizes, int n_in,
                              void* d_out, int out_size, void* d_ws,
                              size_t ws_size, hipStream_t stream) {
  const float* kin = (const float*)d_in[1];  // queries also come from k (ref quirk)
  const float* vin = (const float*)d_in[2];
  const float* Wq = (const float*)d_in[4];
  const float* bq = (const float*)d_in[5];
  const float* Wk = (const float*)d_in[6];
  const float* bk = (const float*)d_in[7];
  const float* Wv = (const float*)d_in[8];
  const float* bv = (const float*)d_in[9];
  const float* Wo = (const float*)d_in[10];
  const float* bo = (const float*)d_in[11];

  float* out = (float*)d_out;
  float* attn = out + (size_t)BS * S_LEN * DMODEL;

  char* ws = (char*)d_ws;
  const size_t MB = (size_t)1 << 20;
  ushort* kb   = (ushort*)(ws + 0 * MB);    // 16 MB; reused as Ah later
  ushort* vb   = (ushort*)(ws + 16 * MB);   // 16 MB (bf16 v tokens)
  ushort* Qh   = (ushort*)(ws + 32 * MB);   // 16 MB
  ushort* Kh   = (ushort*)(ws + 48 * MB);   // 16 MB
  ushort* Vt   = (ushort*)(ws + 64 * MB);   // 16 MB ([d][tok], direct from V GEMM)
  ushort* WqkT = (ushort*)(ws + 80 * MB);   // 4 MB (Wq rows 0..1023, Wk rows 1024..2047)
  ushort* WvT  = (ushort*)(ws + 84 * MB);   // 2 MB
  ushort* WoT  = (ushort*)(ws + 86 * MB);   // 2 MB; total 88 MB

  const int NTOK4 = (BS * S_LEN * DMODEL) / 4;
  cvt2_kernel<<<4096, 256, 0, stream>>>(kin, vin, kb, vb, NTOK4);

  dim3 tb(32, 8);
  transW4_kernel<<<dim3(32, 32, 4), tb, 0, stream>>>(
      Wq, Wk, Wv, Wo, WqkT, WqkT + (size_t)DMODEL * DMODEL, WvT, WoT);

  // merged Q+K projection: N=2048, split epilogue -> Qh, Kh
  gemm_bt<false, true, false><<<64 * 16, 256, 0, stream>>>(
      kb, WqkT, bq, bk, Qh, Kh, 8192, 2048, 1024);
  // V projection with transposed epilogue -> Vt directly (no transV pass)
  gemm_bt<false, false, true><<<64 * 8, 256, 0, stream>>>(
      vb, WvT, bv, nullptr, Vt, nullptr, 8192, 1024, 1024);

  ushort* Ahp = kb;  // kb no longer needed
  attn_kernel<<<BS * NHEAD * (S_LEN / 128), 512, 0, stream>>>(Qh, Kh, Vt, attn, Ahp);

  gemm_bt<true, false, false><<<64 * 8, 256, 0, stream>>>(
      Ahp, WoT, bo, nullptr, out, nullptr, 8192, 1024, 1024);
}

// Round 10
// 392.043 us; speedup vs baseline: 1.1506x; 1.0581x over previous
//
#include <hip/hip_runtime.h>
#include <hip/hip_bf16.h>

#define S_LEN 2048
#define DMODEL 1024
#define NHEAD 16
#define DK 64
#define BS 4

typedef __attribute__((ext_vector_type(8))) short short8;
typedef __attribute__((ext_vector_type(4))) float f32x4;
typedef __attribute__((ext_vector_type(4))) ushort ushort4v;

__device__ __forceinline__ ushort f2b(float f) {
  __hip_bfloat16 h = __float2bfloat16(f);
  return __builtin_bit_cast(ushort, h);
}

__device__ __forceinline__ void gl_lds16(const void* g, void* l) {
  __builtin_amdgcn_global_load_lds(
      (const __attribute__((address_space(1))) void*)g,
      (__attribute__((address_space(3))) void*)l, 16, 0, 0);
}

// ---------------- conversion kernels ----------------

// k and v -> bf16 in one kernel
__global__ __launch_bounds__(256) void cvt2_kernel(
    const float* __restrict__ a, const float* __restrict__ b,
    ushort* __restrict__ oa, ushort* __restrict__ ob, int n4) {
  int idx = blockIdx.x * 256 + threadIdx.x;
  int stride = gridDim.x * 256;
  for (int i = idx; i < 2 * n4; i += stride) {
    const bool first = (i < n4);
    const int j = first ? i : i - n4;
    f32x4 v = first ? ((const f32x4*)a)[j] : ((const f32x4*)b)[j];
    ushort4v o;
    o[0] = f2b(v[0]); o[1] = f2b(v[1]); o[2] = f2b(v[2]); o[3] = f2b(v[3]);
    if (first) ((ushort4v*)oa)[j] = o; else ((ushort4v*)ob)[j] = o;
  }
}

// all four W (1024x1024 f32, K x N) -> Wt (N x K, bf16), z selects which
__global__ __launch_bounds__(256) void transW4_kernel(
    const float* __restrict__ W0, const float* __restrict__ W1,
    const float* __restrict__ W2, const float* __restrict__ W3,
    ushort* __restrict__ T0, ushort* __restrict__ T1,
    ushort* __restrict__ T2, ushort* __restrict__ T3) {
  const float* W;
  ushort* T;
  switch (blockIdx.z) {
    case 0: W = W0; T = T0; break;
    case 1: W = W1; T = T1; break;
    case 2: W = W2; T = T2; break;
    default: W = W3; T = T3; break;
  }
  __shared__ float t[32][33];
  const int n0 = blockIdx.x * 32, k0 = blockIdx.y * 32;
  const int tx = threadIdx.x, ty = threadIdx.y;  // (32,8)
#pragma unroll
  for (int i = 0; i < 4; i++)
    t[ty + i * 8][tx] = W[(size_t)(k0 + ty + i * 8) * DMODEL + n0 + tx];
  __syncthreads();
#pragma unroll
  for (int i = 0; i < 4; i++)
    T[(size_t)(n0 + ty + i * 8) * DMODEL + k0 + tx] = f2b(t[tx][ty + i * 8]);
}

// ---------------- GEMM: C = A(MxK) * Bt(NxK)^T + bias ----------------
// 128x128 tile, BK=32, 256 threads (4 waves 2x2), m97 structure.
// QKMODE: N=2048 merged Q/K projection -> split column halves to Qh/Kh.
// VT: write C^T (bf16) to Cout laid out [N][M] (Vt layout), 8B token packs,
//     normal stores (L2 write-combining; Vt is read right after by attn).
template <bool F32OUT, bool QKMODE, bool VT>
__global__ __launch_bounds__(256) void gemm_bt(
    const ushort* __restrict__ A, const ushort* __restrict__ Bt,
    const float* __restrict__ bias, const float* __restrict__ bias1,
    void* __restrict__ Cout, void* __restrict__ Cout1,
    int M, int N, int K) {
  __shared__ ushort Als[128 * 32];
  __shared__ ushort Bls[128 * 32];
  const int tid = threadIdx.x;
  const int lane = tid & 63;
  const int w = tid >> 6;
  const int lo = lane & 15, hi = lane >> 4;
  const int nb = N >> 7;
  const int bm = blockIdx.x / nb, bn = blockIdx.x % nb;
  const int m0 = bm << 7, n0 = bn << 7;
  const int wr = (w >> 1) << 6, wc = (w & 1) << 6;

  f32x4 acc[4][4] = {};

  const int c1 = tid, c2 = tid + 256;
  const int r1 = c1 >> 2, k1 = (c1 & 3) << 3;
  const int r2 = c2 >> 2, k2 = (c2 & 3) << 3;
  const ushort* Ap1 = A + (size_t)(m0 + r1) * K + k1;
  const ushort* Ap2 = A + (size_t)(m0 + r2) * K + k2;
  const ushort* Bp1 = Bt + (size_t)(n0 + r1) * K + k1;
  const ushort* Bp2 = Bt + (size_t)(n0 + r2) * K + k2;
  char* Al = (char*)Als;
  char* Bl = (char*)Bls;

  for (int k0 = 0; k0 < K; k0 += 32) {
    gl_lds16(Ap1 + k0, Al + c1 * 16);
    gl_lds16(Ap2 + k0, Al + c2 * 16);
    gl_lds16(Bp1 + k0, Bl + c1 * 16);
    gl_lds16(Bp2 + k0, Bl + c2 * 16);
    __syncthreads();
    short8 af[4], bf[4];
#pragma unroll
    for (int i = 0; i < 4; i++)
      af[i] = *(const short8*)(Als + (wr + i * 16 + lo) * 32 + hi * 8);
#pragma unroll
    for (int j = 0; j < 4; j++)
      bf[j] = *(const short8*)(Bls + (wc + j * 16 + lo) * 32 + hi * 8);
#pragma unroll
    for (int i = 0; i < 4; i++)
#pragma unroll
      for (int j = 0; j < 4; j++)
        acc[i][j] = __builtin_amdgcn_mfma_f32_16x16x32_bf16(af[i], bf[j], acc[i][j], 0, 0, 0);
    __syncthreads();
  }

#pragma unroll
  for (int j = 0; j < 4; j++) {
    const int col = n0 + wc + j * 16 + lo;
    const float* bp = (QKMODE && col >= 1024) ? bias1 : bias;
    const int colm = QKMODE ? (col & 1023) : col;
    const int cN = QKMODE ? 1024 : N;
    const float bj = bp ? bp[colm] : 0.0f;
    if (VT) {
      // transposed store: Vt[col][tok], 4-token (8B) packs
#pragma unroll
      for (int i = 0; i < 4; i++) {
        const int row0 = m0 + wr + i * 16 + hi * 4;
        ushort4v pk;
#pragma unroll
        for (int r = 0; r < 4; r++) pk[r] = f2b(acc[i][j][r] + bj);
        *(ushort4v*)(&((ushort*)Cout)[(size_t)col * M + row0]) = pk;
      }
    } else {
#pragma unroll
      for (int i = 0; i < 4; i++) {
        const int row0 = m0 + wr + i * 16 + hi * 4;
#pragma unroll
        for (int r = 0; r < 4; r++) {
          float vv = acc[i][j][r] + bj;
          if (F32OUT) {
            __builtin_nontemporal_store(
                vv, &((float*)Cout)[(size_t)(row0 + r) * N + col]);
          } else {
            void* dst = (QKMODE && col >= 1024) ? Cout1 : Cout;
            ((ushort*)dst)[(size_t)(row0 + r) * cN + colm] = f2b(vv);
          }
        }
      }
    }
  }
}

// ---------------- fused causal attention (swapped QK^T) ----------------
// Block: (b, h, 128-row q-tile), 8 waves, wave owns 16 q-rows (q = w*16+lo).
// S^T = mfma(K_frag, Q_frag): lane (lo,hi) reg r = S[q][k=j*16+hi*4+r]
// -> per-lane scalar softmax denom. P tile -> per-wave swizzled f32 LDS,
// read back row-major for COALESCED attn stores (4 rows x 256B/instr) and
// as bf16 PV A-fragments. K/V staged in LDS (double-buffered,
// global_load_lds, XOR-swizzled source). Zero-fill interleaved in sweep 1.
// Block decode: XCD-grouped (all 16 q-tiles of one (b,h) on one XCD via
// blk%8 round-robin) + heavy/light paired t order (write-pipe balancing:
// co-resident pairs combine a no-write long sweep 1 with a fill-heavy one).
// SWZ: 2-way bank aliasing max on write/read sides (free per m136).
#define SWZ(row) ((((row) & 7) << 5) ^ (((row) & 8) << 1))
__global__ __launch_bounds__(512) void attn_kernel(
    const ushort* __restrict__ Qh, const ushort* __restrict__ Kh,
    const ushort* __restrict__ Vt, float* __restrict__ attn,
    ushort* __restrict__ Ah) {
  const int blk = blockIdx.x;
  // XCD-grouped, heavy/light paired decode
  const int x = blk & 7;          // XCD (assuming blk%8 round-robin)
  const int i2 = blk >> 3;        // per-XCD sequence
  const int g = x + ((i2 >> 4) << 3);  // (b,h) group 0..63; g%8 == x
  const int tidx = i2 & 15;
  const int t = (tidx & 1) ? (tidx >> 1) : (15 - (tidx >> 1));
  const int h = g & 15;
  const int b = g >> 4;
  const int tid = threadIdx.x;
  const int w = tid >> 6;
  const int lane = tid & 63;
  const int lo = lane & 15, hi = lane >> 4;
  const int q0 = t << 7;
  const int qrow = w * 16 + lo;   // q row within the 128-row tile
  const int qg = q0 + qrow;       // absolute q row
  const int tok0 = b * S_LEN + q0 + w * 16;
  const int ktmax = 2 * t + 1;    // last 64-token kv tile (inclusive)
  const int ntiles = ktmax + 1;

  __shared__ ushort Kls[2][64 * 64];  // 2 x 8KB swizzled K tile
  __shared__ ushort Vls[2][64 * 64];  // 2 x 8KB swizzled V tile
  __shared__ float Pf[8][16 * 64];    // per-wave 4KB swizzled f32 P tile

  short8 aq[2];  // Q rows, used as the MFMA B-operand
  {
    const ushort* qp = Qh + (size_t)(tok0 + lo) * DMODEL + h * DK + hi * 8;
    aq[0] = *(const short8*)qp;
    aq[1] = *(const short8*)(qp + 32);
  }

  const ushort* kbh = Kh + (size_t)(b * S_LEN) * DMODEL + h * DK;
  const ushort* vbh = Vt + (size_t)(h * DK) * (BS * S_LEN) + b * S_LEN;

  // staging geometry (proven): 512 threads, row = tid>>3 (0..63),
  // cb_lds = (tid&7)*16; global col bytes = cb_lds ^ ((row&7)<<4)
  const int srow = tid >> 3;
  const int scolb = ((tid & 7) << 4) ^ ((srow & 7) << 4);
  const ushort* ksrc = kbh + (size_t)srow * DMODEL + (scolb >> 1);
  const ushort* vsrc = vbh + (size_t)srow * (BS * S_LEN) + (scolb >> 1);

#define STAGE_K(buf, kt)                                                     \
  gl_lds16(ksrc + (size_t)(kt) * 64 * DMODEL, (char*)&Kls[(buf)][0] + tid * 16)
#define STAGE_V(buf, kt)                                                     \
  gl_lds16(vsrc + (size_t)(kt) * 64, (char*)&Vls[(buf)][0] + tid * 16)

  // K-fragments (A-operand): row = j*16+lo (k token), d = hi*8 (+32)
#define QKT(sa, cur)                                                         \
  __builtin_amdgcn_s_setprio(1);                                             \
  _Pragma("unroll") for (int j = 0; j < 4; j++) {                            \
    const int row = j * 16 + lo;                                             \
    short8 b0 = *(const short8*)((const char*)&Kls[(cur)][0] + row * 128 +   \
                                 ((hi * 16) ^ ((row & 7) << 4)));            \
    sa[j] = __builtin_amdgcn_mfma_f32_16x16x32_bf16(b0, aq[0], sa[j], 0, 0, 0); \
  }                                                                          \
  _Pragma("unroll") for (int j = 0; j < 4; j++) {                            \
    const int row = j * 16 + lo;                                             \
    short8 b1 = *(const short8*)((const char*)&Kls[(cur)][0] + row * 128 +   \
                                 ((64 + hi * 16) ^ ((row & 7) << 4)));       \
    sa[j] = __builtin_amdgcn_mfma_f32_16x16x32_bf16(b1, aq[1], sa[j], 0, 0, 0); \
  }                                                                          \
  __builtin_amdgcn_s_setprio(0);

  float* abase =
      attn + (size_t)(b * NHEAD + h) * S_LEN * S_LEN + (size_t)q0 * S_LEN;

  // zero-fill geometry (masked upper region), interleaved into sweep 1
  const int zc0 = ntiles << 6;        // first masked col
  const int zcol = zc0 + tid * 4;     // this thread's col within a row
  const bool zon = (zcol < S_LEN);
  const f32x4 zv = {0.0f, 0.0f, 0.0f, 0.0f};

  // ---- sweep 1: per-lane partial row sums of exp (K only) + zero-fill ----
  float lsum = 0.0f;
  STAGE_K(0, 0);
  for (int kt = 0; kt <= ktmax; ++kt) {
    const int cur = kt & 1;
    __syncthreads();  // staged data visible; prev buf's readers done
    if (kt < ktmax) STAGE_K(cur ^ 1, kt + 1);
    // interleaved zero-fill chunk: rows [kt*128/ntiles, (kt+1)*128/ntiles)
    if (zon) {
      const int r0 = (kt * 128) / ntiles;
      const int r1 = ((kt + 1) * 128) / ntiles;
      for (int row = r0; row < r1; ++row)
        __builtin_nontemporal_store(
            zv, (f32x4*)(abase + (size_t)row * S_LEN + zcol));
    }
    f32x4 sa[4] = {};
    QKT(sa, cur)
#pragma unroll
    for (int j = 0; j < 4; j++) {
#pragma unroll
      for (int r = 0; r < 4; r++) {
        const int kg = kt * 64 + j * 16 + hi * 4 + r;
        const float e = __expf(sa[j][r] * 0.125f);
        lsum += (kg > qg) ? 0.0f : e;
      }
    }
  }
  // reduce across the 4 hi-groups holding the same q row
  lsum += __shfl_xor(lsum, 16);
  lsum += __shfl_xor(lsum, 32);
  const float invl = 1.0f / lsum;

  // ---- sweep 2: attn write + PV (K and V staged) ----
  f32x4 oacc[4] = {};

  __syncthreads();  // all waves done reading Kls from sweep 1
  STAGE_K(0, 0);
  STAGE_V(0, 0);
  for (int kt = 0; kt <= ktmax; ++kt) {
    const int cur = kt & 1;
    __syncthreads();
    if (kt < ktmax) { STAGE_K(cur ^ 1, kt + 1); STAGE_V(cur ^ 1, kt + 1); }
    f32x4 sa[4] = {};
    QKT(sa, cur)
    // P -> per-wave swizzled f32 LDS tile (16 rows x 64 cols)
#pragma unroll
    for (int j = 0; j < 4; j++) {
      float p[4];
#pragma unroll
      for (int r = 0; r < 4; r++) {
        const int kg = kt * 64 + j * 16 + hi * 4 + r;
        p[r] = (kg > qg) ? 0.0f : __expf(sa[j][r] * 0.125f) * invl;
      }
      f32x4 pv4 = {p[0], p[1], p[2], p[3]};
      *(f32x4*)((char*)&Pf[w][0] + lo * 256 +
                ((j * 64 + hi * 16) ^ SWZ(lo))) = pv4;
    }
    // coalesced attn stores: 4 rows x 256B contiguous per instruction
#pragma unroll
    for (int t2 = 0; t2 < 4; t2++) {
      const int rr = hi + 4 * t2;
      f32x4 pv = *(const f32x4*)((const char*)&Pf[w][0] + rr * 256 +
                                 ((lo * 16) ^ SWZ(rr)));
      __builtin_nontemporal_store(
          pv,
          (f32x4*)(abase + (size_t)(w * 16 + rr) * S_LEN + kt * 64 + lo * 4));
    }
    // PV A-fragments: row = q = lo, k = ks*32 + hi*8 ..+7, from f32 tile
    short8 ap[2];
#pragma unroll
    for (int ks = 0; ks < 2; ks++) {
      const int base = ks * 128 + hi * 32;
      f32x4 u0 = *(const f32x4*)((const char*)&Pf[w][0] + lo * 256 +
                                 ((base) ^ SWZ(lo)));
      f32x4 u1 = *(const f32x4*)((const char*)&Pf[w][0] + lo * 256 +
                                 ((base + 16) ^ SWZ(lo)));
      short8 a;
      a[0] = f2b(u0[0]); a[1] = f2b(u0[1]); a[2] = f2b(u0[2]); a[3] = f2b(u0[3]);
      a[4] = f2b(u1[0]); a[5] = f2b(u1[1]); a[6] = f2b(u1[2]); a[7] = f2b(u1[3]);
      ap[ks] = a;
    }
    __builtin_amdgcn_s_setprio(1);
#pragma unroll
    for (int dj = 0; dj < 4; dj++) {
      const int row = dj * 16 + lo;
      const char* vrow = (const char*)&Vls[cur][0] + row * 128;
      short8 b0 = *(const short8*)(vrow + ((hi * 16) ^ ((row & 7) << 4)));
      short8 b1 = *(const short8*)(vrow + ((64 + hi * 16) ^ ((row & 7) << 4)));
      oacc[dj] = __builtin_amdgcn_mfma_f32_16x16x32_bf16(ap[0], b0, oacc[dj], 0, 0, 0);
      oacc[dj] = __builtin_amdgcn_mfma_f32_16x16x32_bf16(ap[1], b1, oacc[dj], 0, 0, 0);
    }
    __builtin_amdgcn_s_setprio(0);
  }

#pragma unroll
  for (int dj = 0; dj < 4; dj++)
#pragma unroll
    for (int r = 0; r < 4; r++)
      Ah[(size_t)(tok0 + hi * 4 + r) * DMODEL + h * DK + dj * 16 + lo] =
          f2b(oacc[dj][r]);
#undef STAGE_K
#undef STAGE_V
#undef QKT
}

// ---------------- launch ----------------

extern "C" void kernel_launch(void* const* d_in, const int* in_sizes, int n_in,
                              void* d_out, int out_size, void* d_ws,
                              size_t ws_size, hipStream_t stream) {
  const float* kin = (const float*)d_in[1];  // queries also come from k (ref quirk)
  const float* vin = (const float*)d_in[2];
  const float* Wq = (const float*)d_in[4];
  const float* bq = (const float*)d_in[5];
  const float* Wk = (const float*)d_in[6];
  const float* bk = (const float*)d_in[7];
  const float* Wv = (const float*)d_in[8];
  const float* bv = (const float*)d_in[9];
  const float* Wo = (const float*)d_in[10];
  const float* bo = (const float*)d_in[11];

  float* out = (float*)d_out;
  float* attn = out + (size_t)BS * S_LEN * DMODEL;

  char* ws = (char*)d_ws;
  const size_t MB = (size_t)1 << 20;
  ushort* kb   = (ushort*)(ws + 0 * MB);    // 16 MB; reused as Ah later
  ushort* vb   = (ushort*)(ws + 16 * MB);   // 16 MB (bf16 v tokens)
  ushort* Qh   = (ushort*)(ws + 32 * MB);   // 16 MB
  ushort* Kh   = (ushort*)(ws + 48 * MB);   // 16 MB
  ushort* Vt   = (ushort*)(ws + 64 * MB);   // 16 MB ([d][tok], direct from V GEMM)
  ushort* WqkT = (ushort*)(ws + 80 * MB);   // 4 MB (Wq rows 0..1023, Wk rows 1024..2047)
  ushort* WvT  = (ushort*)(ws + 84 * MB);   // 2 MB
  ushort* WoT  = (ushort*)(ws + 86 * MB);   // 2 MB; total 88 MB

  const int NTOK4 = (BS * S_LEN * DMODEL) / 4;
  cvt2_kernel<<<4096, 256, 0, stream>>>(kin, vin, kb, vb, NTOK4);

  dim3 tb(32, 8);
  transW4_kernel<<<dim3(32, 32, 4), tb, 0, stream>>>(
      Wq, Wk, Wv, Wo, WqkT, WqkT + (size_t)DMODEL * DMODEL, WvT, WoT);

  // merged Q+K projection: N=2048, split epilogue -> Qh, Kh
  gemm_bt<false, true, false><<<64 * 16, 256, 0, stream>>>(
      kb, WqkT, bq, bk, Qh, Kh, 8192, 2048, 1024);
  // V projection with transposed epilogue -> Vt directly (no transV pass)
  gemm_bt<false, false, true><<<64 * 8, 256, 0, stream>>>(
      vb, WvT, bv, nullptr, Vt, nullptr, 8192, 1024, 1024);

  ushort* Ahp = kb;  // kb no longer needed
  attn_kernel<<<BS * NHEAD * (S_LEN / 128), 512, 0, stream>>>(Qh, Kh, Vt, attn, Ahp);

  gemm_bt<true, false, false><<<64 * 8, 256, 0, stream>>>(
      Ahp, WoT, bo, nullptr, out, nullptr, 8192, 1024, 1024);
}